// Round 3
// baseline (610.189 us; speedup 1.0000x reference)
//
#include <hip/hip_runtime.h>
#include <hip/hip_cooperative_groups.h>
namespace cg = cooperative_groups;

#define NB 8
#define NN 10000
#define NE 160000
#define NNODES (NB*NN)          // 80000
#define NEDGE (NB*NE)           // 1280000
#define FIN 5
#define HID 128
#define EMB 256
#define ALAST 10
#define PROJ_IN (HID*5 + ALAST + 1)  // 651
#define NPOS 40                      // 5 positions x 8 batches
#define E0CAP 256                    // in-edges kept per position node
#define TCAP (NPOS + NPOS*E0CAP)     // 10280 max T slots (realistically ~720)
#define E1C 128                      // in-edges kept per T slot (Poisson(16))
#define NBLK ((NNODES+255)/256)      // 313
#define KC 32

// markT encoding: -1 none, >=0 T slot, -2 transient CAS claim, -3 degree-needed-only
// cnts: [0]=nT; per-position e0 counters at stride-16 ints (64B padded).
#define C_NT 0
#define C_E0(t) (8 + (t)*16)

// -------- shared-memory union for the fused kernel's phases --------
struct SmemH12 {
    float axs[FIN][128];
    float w1s[FIN][128];
    float b1s[128];
    float dvs[128];
    float xs[KC*128];
    float wt[KC*64];
};
struct SmemMlp1 {
    float c[PROJ_IN];
    int slots[5*E1C];
    int cm[5], t0s[5];
    float dvP[5];
};
struct SmemInit { int pnode[NPOS]; int pslot[NPOS]; };
struct SmemDD   { int lc; int base; };
union SmemAll {
    SmemH12  h12;   // 30720 B (max)
    SmemMlp1 m1;
    SmemInit init;
    SmemDD   dd;
    float    c2[EMB];
};

// ================= fused persistent cooperative kernel =================
__global__ __launch_bounds__(256, 4) void k_all(
        const float* __restrict__ xg, const int* __restrict__ edges,
        const int* __restrict__ pos, const int* __restrict__ avail,
        const float* __restrict__ actions, const float* __restrict__ steps,
        const float* __restrict__ W1, const float* __restrict__ b1,
        const float* __restrict__ W2, const float* __restrict__ b2,
        const float* __restrict__ Wp1, const float* __restrict__ bp1,
        const float* __restrict__ Wp2, const float* __restrict__ bp2,
        float* __restrict__ out,
        int* __restrict__ markT, int* __restrict__ degCnt,
        int* __restrict__ cnts, int* __restrict__ e1cnt,
        int* __restrict__ Tnodes, int* __restrict__ pos2t0,
        int* __restrict__ posNode, int* __restrict__ e0,
        int* __restrict__ e1, float* __restrict__ axT,
        float* __restrict__ hsT, float* __restrict__ hm)
{
    cg::grid_group gg = cg::this_grid();
    __shared__ SmemAll sm;
    const int tid  = threadIdx.x;
    const int bid  = blockIdx.x;
    const int nbk  = gridDim.x;
    const int gtid = bid*256 + tid;
    const int nthr = nbk*256;

    // ---------- phase 0: clear + position-mark ----------
    if (tid < 64) {                      // wave 0 of every block: 40-pos dedupe
        int p = tid, n = -1;
        if (p < NPOS) {
            int b = p / 5, pi = p - b*5;
            int node = (pi < 4) ? avail[b*4 + pi] : pos[b];
            n = node + b*NN;
        }
        int firstIdx = p;
        for (int q = 0; q < NPOS; ++q) {
            int nq = __shfl(n, q, 64);
            if (p < NPOS && q < p && nq == n && firstIdx == p) firstIdx = q;
        }
        bool isFirst = (p < NPOS) && (firstIdx == p);
        unsigned long long bal = __ballot(isFirst);
        if (p < NPOS) {
            int slot = __popcll(bal & ((1ull << firstIdx) - 1ull));
            sm.init.pnode[p] = n;
            sm.init.pslot[p] = slot;
            if (bid == 0) {
                pos2t0[p] = slot; posNode[p] = n;
                if (isFirst) Tnodes[slot] = n;
            }
        }
        if (p == 0 && bid == 0) cnts[C_NT] = __popcll(bal);
    }
    __syncthreads();
    for (int i = gtid; i < NNODES; i += nthr) {
        int mk = -1;
        #pragma unroll
        for (int p = 0; p < NPOS; ++p)
            if (i == sm.init.pnode[p]) mk = sm.init.pslot[p];
        markT[i] = mk;
        degCnt[i] = 0;
    }
    for (int i = gtid; i < 1024; i += nthr) if (i != C_NT) cnts[i] = 0;
    for (int j = gtid; j < TCAP*4; j += nthr) e1cnt[j] = 0;
    gg.sync();

    // ---------- phase 1: pass1 (edges into T0 -> e0 lists) ----------
    for (int q = gtid; q < NEDGE/4; q += nthr) {
        int g = q / (NE/4), w4 = q - g*(NE/4);
        const int* base = edges + (size_t)g*2*NE;
        int4 d4 = ((const int4*)(base + NE))[w4];
        int gofs = g*NN;
        int dd4[4] = {d4.x, d4.y, d4.z, d4.w};
        #pragma unroll
        for (int c = 0; c < 4; ++c) {
            int t0 = markT[gofs + dd4[c]];
            if (t0 >= 0) {
                int s = base[4*w4 + c] + gofs;
                int k = atomicAdd(&cnts[C_E0(t0)], 1);
                if (k < E0CAP) e0[t0*E0CAP + k] = s;
            }
        }
    }
    gg.sync();

    // ---------- phase 2: dedup (blocks 0..39) ----------
    if (bid < NPOS) {
        if (tid == 0) sm.dd.lc = 0;
        __syncthreads();
        int m = cnts[C_E0(bid)]; if (m > E0CAP) m = E0CAP;
        int s = -1, myIdx = -1;
        if (tid < m) {
            s = e0[bid*E0CAP + tid];
            if (atomicCAS(&markT[s], -1, -2) == -1)
                myIdx = atomicAdd(&sm.dd.lc, 1);
        }
        __syncthreads();
        if (tid == 0 && sm.dd.lc > 0) sm.dd.base = atomicAdd(&cnts[C_NT], sm.dd.lc);
        __syncthreads();
        if (myIdx >= 0) {
            int slot = sm.dd.base + myIdx;
            Tnodes[slot] = s;
            markT[s] = slot;
        }
    }
    gg.sync();

    // ---------- phase 3: pass2 (edges into T -> e1 lists; T degree; -3 marks) ----------
    for (int q = gtid; q < NEDGE/4; q += nthr) {
        int g = q / (NE/4), w4 = q - g*(NE/4);
        const int* base = edges + (size_t)g*2*NE;
        int4 d4 = ((const int4*)(base + NE))[w4];
        int gofs = g*NN;
        int dd4[4] = {d4.x, d4.y, d4.z, d4.w};
        #pragma unroll
        for (int c = 0; c < 4; ++c) {
            int d = gofs + dd4[c];
            int ts = markT[d];
            if (ts >= 0) {
                int s = base[4*w4 + c] + gofs;
                int k = atomicAdd(&e1cnt[ts*4], 1);
                if (k < E1C) e1[(size_t)ts*E1C + k] = s;
                atomicAdd(&degCnt[d], 1);
                if (markT[s] == -1) markT[s] = -3;   // benign same-value race
            }
        }
    }
    gg.sync();

    // ---------- phase 4: pass3 (degrees of -3 sources) ----------
    for (int q = gtid; q < NEDGE/4; q += nthr) {
        int g = q / (NE/4), w4 = q - g*(NE/4);
        int4 d4 = ((const int4*)(edges + (size_t)g*2*NE + NE))[w4];
        int gofs = g*NN;
        int dd4[4] = {d4.x, d4.y, d4.z, d4.w};
        #pragma unroll
        for (int c = 0; c < 4; ++c) {
            int n = gofs + dd4[c];
            if (markT[n] == -3) atomicAdd(&degCnt[n], 1);
        }
    }
    gg.sync();

    // ---------- phase 5: aggT (wave per slot) ----------
    int ntv = cnts[C_NT]; if (ntv > TCAP) ntv = TCAP;
    {
        int lane = tid & 63;
        for (int slot = bid*4 + (tid >> 6); slot < ntv; slot += nbk*4) {
            int m = e1cnt[slot*4]; if (m > E1C) m = E1C;
            float acc[FIN] = {0.f, 0.f, 0.f, 0.f, 0.f};
            for (int j = lane; j < m; j += 64) {
                int s = e1[(size_t)slot*E1C + j];
                float dv = rsqrtf(1.0f + (float)degCnt[s]);
                const float* xr = xg + (size_t)s*FIN;
                #pragma unroll
                for (int f = 0; f < FIN; ++f) acc[f] += xr[f]*dv;
            }
            #pragma unroll
            for (int f = 0; f < FIN; ++f) {
                #pragma unroll
                for (int d = 32; d; d >>= 1) acc[f] += __shfl_down(acc[f], d, 64);
            }
            if (lane == 0) {
                #pragma unroll
                for (int f = 0; f < FIN; ++f) axT[(size_t)slot*FIN + f] = acc[f];
            }
        }
    }
    gg.sync();

    // ---------- phase 6: h12T (fused dense L1+L2 over T) ----------
    {
        int nblk6 = 2*((ntv + 127)/128);
        int tx = tid & 15, ty = tid >> 4;
        int m0 = ty*8, j0 = tx*4;
        int r  = tid >> 1, kq = (tid & 1)*16;
        int rw = tid >> 2, kqw = (tid & 3)*8;
        for (int b6 = bid; b6 < nblk6; b6 += nbk) {
            int jb  = b6 & 1;
            int m0g = (b6 >> 1)*128;
            if (tid < 128) {
                sm.h12.b1s[tid] = b1[tid];
                #pragma unroll
                for (int f = 0; f < FIN; ++f) sm.h12.w1s[f][tid] = W1[tid*FIN + f];
            } else {
                int r2 = tid - 128;
                int row = m0g + r2;
                int ok = row < ntv;
                int node = ok ? Tnodes[row] : 0;
                float dvv = ok ? rsqrtf(1.0f + (float)degCnt[node]) : 0.0f;
                sm.h12.dvs[r2] = dvv;
                #pragma unroll
                for (int f = 0; f < FIN; ++f)
                    sm.h12.axs[f][r2] = ok ? (axT[(size_t)row*FIN + f]
                                              + xg[(size_t)node*FIN + f]*dvv) : 0.0f;
            }
            float a[8][4];
            #pragma unroll
            for (int i = 0; i < 8; ++i)
                #pragma unroll
                for (int j = 0; j < 4; ++j) a[i][j] = 0.f;
            __syncthreads();
            float axr[FIN];
            float dvr = sm.h12.dvs[r];
            #pragma unroll
            for (int f = 0; f < FIN; ++f) axr[f] = sm.h12.axs[f][r] * dvr;

            for (int kh = 0; kh < 128; kh += KC) {
                float4 wv0 = *(const float4*)&W2[(size_t)(jb*64 + rw)*128 + kh + kqw];
                float4 wv1 = *(const float4*)&W2[(size_t)(jb*64 + rw)*128 + kh + kqw + 4];
                float hv[16];
                #pragma unroll
                for (int kk = 0; kk < 16; ++kk) {
                    int k1 = kh + kq + kk;
                    float sv = sm.h12.b1s[k1];
                    #pragma unroll
                    for (int f = 0; f < FIN; ++f) sv += axr[f]*sm.h12.w1s[f][k1];
                    hv[kk] = fmaxf(sv, 0.0f);
                }
                __syncthreads();
                #pragma unroll
                for (int kk = 0; kk < 16; ++kk) sm.h12.xs[(kq+kk)*128 + r] = hv[kk];
                sm.h12.wt[(kqw+0)*64 + rw] = wv0.x;
                sm.h12.wt[(kqw+1)*64 + rw] = wv0.y;
                sm.h12.wt[(kqw+2)*64 + rw] = wv0.z;
                sm.h12.wt[(kqw+3)*64 + rw] = wv0.w;
                sm.h12.wt[(kqw+4)*64 + rw] = wv1.x;
                sm.h12.wt[(kqw+5)*64 + rw] = wv1.y;
                sm.h12.wt[(kqw+6)*64 + rw] = wv1.z;
                sm.h12.wt[(kqw+7)*64 + rw] = wv1.w;
                __syncthreads();
                for (int k = 0; k < KC; ++k) {
                    float4 xa = *(const float4*)&sm.h12.xs[k*128 + m0];
                    float4 xb = *(const float4*)&sm.h12.xs[k*128 + m0 + 4];
                    float4 wa = *(const float4*)&sm.h12.wt[k*64 + j0];
                    float xr[8] = {xa.x,xa.y,xa.z,xa.w,xb.x,xb.y,xb.z,xb.w};
                    #pragma unroll
                    for (int i = 0; i < 8; ++i) {
                        a[i][0] += xr[i]*wa.x;
                        a[i][1] += xr[i]*wa.y;
                        a[i][2] += xr[i]*wa.z;
                        a[i][3] += xr[i]*wa.w;
                    }
                }
            }
            #pragma unroll
            for (int i = 0; i < 8; ++i) {
                int row = m0g + m0 + i;
                if (row < ntv) {
                    float dv = sm.h12.dvs[m0 + i];
                    float4 v0 = make_float4(a[i][0]*dv, a[i][1]*dv, a[i][2]*dv, a[i][3]*dv);
                    *(float4*)&hsT[(size_t)row*HID + jb*64 + j0] = v0;
                }
            }
            __syncthreads();     // protect sm.h12 before next iteration
        }
    }
    gg.sync();

    // ---------- phase 7: mlp1 (fused L2-agg + proj1) ----------
    for (int b7 = bid; b7 < NB*16; b7 += nbk) {
        int b  = b7 >> 4;
        int jg = b7 & 15;
        if (tid < 5) {
            int t0 = pos2t0[b*5 + tid];
            sm.m1.t0s[tid] = t0;
            int m = e1cnt[t0*4]; if (m > E1C) m = E1C;
            sm.m1.cm[tid] = m;
            sm.m1.dvP[tid] = rsqrtf(1.0f + (float)degCnt[posNode[b*5 + tid]]);
        }
        __syncthreads();
        for (int i = tid; i < 5*E1C; i += 256) {
            int p5 = i >> 7, j = i & (E1C-1);
            if (j < sm.m1.cm[p5]) sm.m1.slots[i] = markT[e1[(size_t)sm.m1.t0s[p5]*E1C + j]];
        }
        __syncthreads();
        for (int i = tid; i < 5*HID; i += 256) {
            int p5 = i >> 7, f = i & 127;
            float acc = hsT[(size_t)sm.m1.t0s[p5]*HID + f];
            int m = sm.m1.cm[p5];
            const int* sp = &sm.m1.slots[p5*E1C];
            for (int j = 0; j < m; ++j) {
                int ts = sp[j];
                if (ts >= 0) acc += hsT[(size_t)ts*HID + f];
            }
            sm.m1.c[i] = fmaxf(acc*sm.m1.dvP[p5] + b2[f], 0.0f);
        }
        if (tid < ALAST) sm.m1.c[5*HID + tid] = actions[b*ALAST + tid];
        if (tid == ALAST) sm.m1.c[5*HID + ALAST] = steps[b];
        __syncthreads();
        {
            int o = tid >> 4, sub = tid & 15;
            int j = jg*16 + o;
            const float* wr = Wp1 + (size_t)j*PROJ_IN;
            float s = 0.f;
            for (int k = sub; k < PROJ_IN; k += 16) s += sm.m1.c[k]*wr[k];
            #pragma unroll
            for (int d = 8; d; d >>= 1) s += __shfl_down(s, d, 16);
            if (sub == 0) hm[b*EMB + j] = fmaxf(s + bp1[j], 0.f);
        }
        __syncthreads();     // protect sm.m1 before next iteration
    }
    gg.sync();

    // ---------- phase 8: mlp2 ----------
    for (int b8 = bid; b8 < NB*16; b8 += nbk) {
        int b  = b8 >> 4;
        int jg = b8 & 15;
        if (tid < EMB) sm.c2[tid] = hm[b*EMB + tid];
        __syncthreads();
        {
            int o = tid >> 4, sub = tid & 15;
            int j = jg*16 + o;
            const float* wr = Wp2 + (size_t)j*EMB;
            float s = 0.f;
            for (int k = sub; k < EMB; k += 16) s += sm.c2[k]*wr[k];
            #pragma unroll
            for (int d = 8; d; d >>= 1) s += __shfl_down(s, d, 16);
            if (sub == 0) out[b*EMB + j] = s + bp2[j];
        }
        __syncthreads();
    }
}

// ================= legacy 9-kernel path (fallback) =================

__global__ __launch_bounds__(256) void k_init(
        const int* __restrict__ avail, const int* __restrict__ pos,
        int* __restrict__ markT, int* __restrict__ degCnt,
        int* __restrict__ cnts, int* __restrict__ e1cnt,
        int* __restrict__ Tnodes, int* __restrict__ pos2t0,
        int* __restrict__ posNode) {
    __shared__ int pnode[NPOS];
    __shared__ int pslot[NPOS];
    int t = threadIdx.x;
    if (t < 64) {
        int p = t, n = -1;
        if (p < NPOS) {
            int b = p / 5, pi = p - b*5;
            int node = (pi < 4) ? avail[b*4 + pi] : pos[b];
            n = node + b*NN;
        }
        int firstIdx = p;
        for (int q = 0; q < NPOS; ++q) {
            int nq = __shfl(n, q, 64);
            if (p < NPOS && q < p && nq == n && firstIdx == p) firstIdx = q;
        }
        bool isFirst = (p < NPOS) && (firstIdx == p);
        unsigned long long bal = __ballot(isFirst);
        if (p < NPOS) {
            int slot = __popcll(bal & ((1ull << firstIdx) - 1ull));
            pnode[p] = n;
            pslot[p] = slot;
            if (blockIdx.x == 0) {
                pos2t0[p] = slot; posNode[p] = n;
                if (isFirst) Tnodes[slot] = n;
            }
        }
        if (p == 0 && blockIdx.x == 0) cnts[C_NT] = __popcll(bal);
    }
    __syncthreads();
    int i = blockIdx.x*256 + t;
    if (i < NNODES) {
        int mk = -1;
        #pragma unroll
        for (int p = 0; p < NPOS; ++p)
            if (i == pnode[p]) mk = pslot[p];
        markT[i] = mk;
        degCnt[i] = 0;
    }
    if (i >= 1 && i < 1024) cnts[i] = 0;
    for (int j = i; j < TCAP*4; j += NNODES) e1cnt[j] = 0;
}

__global__ __launch_bounds__(256) void k_pass1(const int* __restrict__ edges,
        const int* __restrict__ markT, int* __restrict__ cnts,
        int* __restrict__ e0) {
    int idx = blockIdx.x*256 + threadIdx.x;
    int g = idx / (NE/4), w4 = idx - g*(NE/4);
    const int* base = edges + (size_t)g*2*NE;
    int4 d4 = ((const int4*)(base + NE))[w4];
    int gofs = g*NN;
    int dd[4] = {d4.x, d4.y, d4.z, d4.w};
    #pragma unroll
    for (int c = 0; c < 4; ++c) {
        int t0 = markT[gofs + dd[c]];
        if (t0 >= 0) {
            int s = base[4*w4 + c] + gofs;
            int k = atomicAdd(&cnts[C_E0(t0)], 1);
            if (k < E0CAP) e0[t0*E0CAP + k] = s;
        }
    }
}

__global__ __launch_bounds__(256) void k_dedup(const int* __restrict__ e0,
                        int* __restrict__ cnts, int* __restrict__ markT,
                        int* __restrict__ Tnodes) {
    __shared__ int lc, base;
    int t0 = blockIdx.x;
    if (threadIdx.x == 0) lc = 0;
    __syncthreads();
    int m = cnts[C_E0(t0)]; if (m > E0CAP) m = E0CAP;
    int s = -1, myIdx = -1;
    if ((int)threadIdx.x < m) {
        s = e0[t0*E0CAP + threadIdx.x];
        if (atomicCAS(&markT[s], -1, -2) == -1)
            myIdx = atomicAdd(&lc, 1);
    }
    __syncthreads();
    if (threadIdx.x == 0 && lc > 0) base = atomicAdd(&cnts[C_NT], lc);
    __syncthreads();
    if (myIdx >= 0) {
        int slot = base + myIdx;
        Tnodes[slot] = s;
        markT[s] = slot;
    }
}

__global__ __launch_bounds__(256) void k_pass2(const int* __restrict__ edges,
        int* __restrict__ markT, int* __restrict__ e1cnt, int* __restrict__ e1,
        int* __restrict__ degCnt) {
    int idx = blockIdx.x*256 + threadIdx.x;
    int g = idx / (NE/4), w4 = idx - g*(NE/4);
    const int* base = edges + (size_t)g*2*NE;
    int4 d4 = ((const int4*)(base + NE))[w4];
    int gofs = g*NN;
    int dd[4] = {d4.x, d4.y, d4.z, d4.w};
    #pragma unroll
    for (int c = 0; c < 4; ++c) {
        int d = gofs + dd[c];
        int ts = markT[d];
        if (ts >= 0) {
            int s = base[4*w4 + c] + gofs;
            int k = atomicAdd(&e1cnt[ts*4], 1);
            if (k < E1C) e1[(size_t)ts*E1C + k] = s;
            atomicAdd(&degCnt[d], 1);
            if (markT[s] == -1) markT[s] = -3;
        }
    }
}

__global__ __launch_bounds__(256) void k_pass3(const int* __restrict__ edges,
        const int* __restrict__ markT, int* __restrict__ degCnt) {
    int idx = blockIdx.x*256 + threadIdx.x;
    int g = idx / (NE/4), w4 = idx - g*(NE/4);
    int4 d4 = ((const int4*)(edges + (size_t)g*2*NE + NE))[w4];
    int gofs = g*NN;
    int dd[4] = {d4.x, d4.y, d4.z, d4.w};
    #pragma unroll
    for (int c = 0; c < 4; ++c) {
        int n = gofs + dd[c];
        if (markT[n] == -3) atomicAdd(&degCnt[n], 1);
    }
}

__global__ __launch_bounds__(256) void k_aggT(
        const int* __restrict__ e1cnt, const int* __restrict__ e1,
        const int* __restrict__ degCnt, const int* __restrict__ cnts,
        const float* __restrict__ xg, float* __restrict__ axT) {
    int slot = blockIdx.x*4 + (threadIdx.x >> 6);
    int lane = threadIdx.x & 63;
    int ntv = cnts[C_NT]; if (ntv > TCAP) ntv = TCAP;
    if (slot >= ntv) return;
    int m = e1cnt[slot*4]; if (m > E1C) m = E1C;
    float acc[FIN] = {0.f, 0.f, 0.f, 0.f, 0.f};
    for (int j = lane; j < m; j += 64) {
        int s = e1[(size_t)slot*E1C + j];
        float dv = rsqrtf(1.0f + (float)degCnt[s]);
        const float* xr = xg + (size_t)s*FIN;
        #pragma unroll
        for (int f = 0; f < FIN; ++f) acc[f] += xr[f]*dv;
    }
    #pragma unroll
    for (int f = 0; f < FIN; ++f) {
        #pragma unroll
        for (int d = 32; d; d >>= 1) acc[f] += __shfl_down(acc[f], d, 64);
    }
    if (lane == 0) {
        #pragma unroll
        for (int f = 0; f < FIN; ++f) axT[(size_t)slot*FIN + f] = acc[f];
    }
}

__global__ __launch_bounds__(256) void k_h12T(
        const float* __restrict__ axT, const int* __restrict__ Tnodes,
        const int* __restrict__ degCnt, const int* __restrict__ cnts,
        const float* __restrict__ xg,
        const float* __restrict__ W1, const float* __restrict__ b1,
        const float* __restrict__ W2, float* __restrict__ hsT) {
    __shared__ float axs[FIN][128];
    __shared__ float w1s[FIN][128];
    __shared__ float b1s[128];
    __shared__ float dvs[128];
    __shared__ float xs[KC*128];
    __shared__ float wt[KC*64];
    int ntv = cnts[C_NT]; if (ntv > TCAP) ntv = TCAP;
    int jb  = blockIdx.x & 1;
    int m0g = (blockIdx.x >> 1) * 128;
    if (m0g >= ntv) return;
    int tid = threadIdx.x;
    if (tid < 128) {
        b1s[tid] = b1[tid];
        #pragma unroll
        for (int f = 0; f < FIN; ++f) w1s[f][tid] = W1[tid*FIN + f];
    } else {
        int r2 = tid - 128;
        int row = m0g + r2;
        int ok = row < ntv;
        int node = ok ? Tnodes[row] : 0;
        float dvv = ok ? rsqrtf(1.0f + (float)degCnt[node]) : 0.0f;
        dvs[r2] = dvv;
        #pragma unroll
        for (int f = 0; f < FIN; ++f)
            axs[f][r2] = ok ? (axT[(size_t)row*FIN + f]
                               + xg[(size_t)node*FIN + f]*dvv) : 0.0f;
    }
    int tx = tid & 15, ty = tid >> 4;
    int m0 = ty*8;
    int j0 = tx*4;
    int r  = tid >> 1;
    int kq = (tid & 1) * 16;
    int rw  = tid >> 2;
    int kqw = (tid & 3) * 8;
    float a[8][4];
    #pragma unroll
    for (int i = 0; i < 8; ++i)
        #pragma unroll
        for (int j = 0; j < 4; ++j) a[i][j] = 0.f;
    __syncthreads();
    float axr[FIN];
    float dvr = dvs[r];
    #pragma unroll
    for (int f = 0; f < FIN; ++f) axr[f] = axs[f][r] * dvr;

    for (int kh = 0; kh < 128; kh += KC) {
        float4 wv0 = *(const float4*)&W2[(size_t)(jb*64 + rw)*128 + kh + kqw];
        float4 wv1 = *(const float4*)&W2[(size_t)(jb*64 + rw)*128 + kh + kqw + 4];
        float hv[16];
        #pragma unroll
        for (int kk = 0; kk < 16; ++kk) {
            int k1 = kh + kq + kk;
            float sv = b1s[k1];
            #pragma unroll
            for (int f = 0; f < FIN; ++f) sv += axr[f]*w1s[f][k1];
            hv[kk] = fmaxf(sv, 0.0f);
        }
        __syncthreads();
        #pragma unroll
        for (int kk = 0; kk < 16; ++kk) xs[(kq+kk)*128 + r] = hv[kk];
        wt[(kqw+0)*64 + rw] = wv0.x;
        wt[(kqw+1)*64 + rw] = wv0.y;
        wt[(kqw+2)*64 + rw] = wv0.z;
        wt[(kqw+3)*64 + rw] = wv0.w;
        wt[(kqw+4)*64 + rw] = wv1.x;
        wt[(kqw+5)*64 + rw] = wv1.y;
        wt[(kqw+6)*64 + rw] = wv1.z;
        wt[(kqw+7)*64 + rw] = wv1.w;
        __syncthreads();
        for (int k = 0; k < KC; ++k) {
            float4 xa = *(const float4*)&xs[k*128 + m0];
            float4 xb = *(const float4*)&xs[k*128 + m0 + 4];
            float4 wa = *(const float4*)&wt[k*64 + j0];
            float xr[8] = {xa.x,xa.y,xa.z,xa.w,xb.x,xb.y,xb.z,xb.w};
            #pragma unroll
            for (int i = 0; i < 8; ++i) {
                a[i][0] += xr[i]*wa.x;
                a[i][1] += xr[i]*wa.y;
                a[i][2] += xr[i]*wa.z;
                a[i][3] += xr[i]*wa.w;
            }
        }
    }
    #pragma unroll
    for (int i = 0; i < 8; ++i) {
        int row = m0g + m0 + i;
        if (row < ntv) {
            float dv = dvs[m0 + i];
            float4 v0 = make_float4(a[i][0]*dv, a[i][1]*dv, a[i][2]*dv, a[i][3]*dv);
            *(float4*)&hsT[(size_t)row*HID + jb*64 + j0] = v0;
        }
    }
}

__global__ __launch_bounds__(256) void k_mlp1(
        const int* __restrict__ pos2t0, const int* __restrict__ posNode,
        const int* __restrict__ e1cnt, const int* __restrict__ e1,
        const int* __restrict__ markT, const float* __restrict__ hsT,
        const int* __restrict__ degCnt, const float* __restrict__ b2,
        const float* __restrict__ actions, const float* __restrict__ steps,
        const float* __restrict__ Wp1, const float* __restrict__ bp1,
        float* __restrict__ hm) {
    int b  = blockIdx.x >> 4;
    int jg = blockIdx.x & 15;
    int t  = threadIdx.x;
    __shared__ float c[PROJ_IN];
    __shared__ int slots[5*E1C];
    __shared__ int cm[5], t0s[5];
    __shared__ float dvP[5];
    if (t < 5) {
        int t0 = pos2t0[b*5 + t];
        t0s[t] = t0;
        int m = e1cnt[t0*4]; if (m > E1C) m = E1C;
        cm[t] = m;
        dvP[t] = rsqrtf(1.0f + (float)degCnt[posNode[b*5 + t]]);
    }
    __syncthreads();
    for (int i = t; i < 5*E1C; i += 256) {
        int p5 = i >> 7, j = i & (E1C-1);
        if (j < cm[p5]) slots[i] = markT[e1[(size_t)t0s[p5]*E1C + j]];
    }
    __syncthreads();
    for (int i = t; i < 5*HID; i += 256) {
        int p5 = i >> 7, f = i & 127;
        float acc = hsT[(size_t)t0s[p5]*HID + f];
        int m = cm[p5];
        const int* sp = &slots[p5*E1C];
        for (int j = 0; j < m; ++j) {
            int ts = sp[j];
            if (ts >= 0) acc += hsT[(size_t)ts*HID + f];
        }
        c[i] = fmaxf(acc*dvP[p5] + b2[f], 0.0f);
    }
    if (t < ALAST) c[5*HID + t] = actions[b*ALAST + t];
    if (t == ALAST) c[5*HID + ALAST] = steps[b];
    __syncthreads();
    int o = t >> 4, sub = t & 15;
    int j = jg*16 + o;
    const float* wr = Wp1 + (size_t)j*PROJ_IN;
    float s = 0.f;
    for (int k = sub; k < PROJ_IN; k += 16) s += c[k]*wr[k];
    #pragma unroll
    for (int d = 8; d; d >>= 1) s += __shfl_down(s, d, 16);
    if (sub == 0) hm[b*EMB + j] = fmaxf(s + bp1[j], 0.f);
}

__global__ __launch_bounds__(256) void k_mlp2(
        const float* __restrict__ hm, const float* __restrict__ Wp2,
        const float* __restrict__ bp2, float* __restrict__ out) {
    int b  = blockIdx.x >> 4;
    int jg = blockIdx.x & 15;
    int t  = threadIdx.x;
    __shared__ float c[EMB];
    if (t < EMB) c[t] = hm[b*EMB + t];
    __syncthreads();
    int o = t >> 4, sub = t & 15;
    int j = jg*16 + o;
    const float* wr = Wp2 + (size_t)j*EMB;
    float s = 0.f;
    for (int k = sub; k < EMB; k += 16) s += c[k]*wr[k];
    #pragma unroll
    for (int d = 8; d; d >>= 1) s += __shfl_down(s, d, 16);
    if (sub == 0) out[b*EMB + j] = s + bp2[j];
}

extern "C" void kernel_launch(void* const* d_in, const int* in_sizes, int n_in,
                              void* d_out, int out_size, void* d_ws, size_t ws_size,
                              hipStream_t stream) {
    const float* graph_x = (const float*)d_in[0];
    const int*   edges   = (const int*)d_in[1];
    const int*   pos     = (const int*)d_in[2];
    const int*   avail   = (const int*)d_in[3];
    const float* actions = (const float*)d_in[4];
    const float* steps   = (const float*)d_in[5];
    const float* W1  = (const float*)d_in[6];
    const float* b1  = (const float*)d_in[7];
    const float* W2  = (const float*)d_in[8];
    const float* b2  = (const float*)d_in[9];
    const float* Wp1 = (const float*)d_in[10];
    const float* bp1 = (const float*)d_in[11];
    const float* Wp2 = (const float*)d_in[12];
    const float* bp2 = (const float*)d_in[13];
    float* out = (float*)d_out;

    char* ws = (char*)d_ws;
    size_t off = 0;
    #define ALLOC(ptrname, type, nelem) \
        type* ptrname = (type*)(ws + off); off = (off + (size_t)(nelem)*sizeof(type) + 255) & ~(size_t)255;
    ALLOC(markT,   int,   NNODES)
    ALLOC(degCnt,  int,   NNODES)
    ALLOC(cnts,    int,   1024)
    ALLOC(e1cnt,   int,   TCAP*4)
    ALLOC(Tnodes,  int,   TCAP)
    ALLOC(pos2t0,  int,   NPOS)
    ALLOC(posNode, int,   NPOS)
    ALLOC(e0,      int,   NPOS*E0CAP)
    ALLOC(e1,      int,   (size_t)TCAP*E1C)
    ALLOC(axT,     float, (size_t)(TCAP+128)*FIN)
    ALLOC(hsT,     float, (size_t)TCAP*HID)
    ALLOC(hm,      float, (size_t)NB*EMB)
    #undef ALLOC

    // ---- cooperative fused path ----
    static int s_grid = 0;
    if (s_grid == 0) {
        int nbm = 0;
        if (hipOccupancyMaxActiveBlocksPerMultiprocessor(&nbm, k_all, 256, 0) != hipSuccess
            || nbm < 1) nbm = 4;
        long g = (long)nbm * 256;          // 256 CUs on MI355X
        if (g > 1280) g = 1280;
        if (g < 64)   g = 64;
        s_grid = (int)g;
    }
    void* params[] = { &graph_x, &edges, &pos, &avail, &actions, &steps,
                       &W1, &b1, &W2, &b2, &Wp1, &bp1, &Wp2, &bp2, &out,
                       &markT, &degCnt, &cnts, &e1cnt, &Tnodes, &pos2t0,
                       &posNode, &e0, &e1, &axT, &hsT, &hm };
    hipError_t err = hipLaunchCooperativeKernel((void*)k_all, dim3(s_grid), dim3(256),
                                                params, 0, stream);
    if (err == hipSuccess) return;

    // ---- legacy fallback (9 kernels) ----
    (void)hipGetLastError();
    k_init<<<NBLK, 256, 0, stream>>>(avail, pos, markT, degCnt, cnts, e1cnt,
                                     Tnodes, pos2t0, posNode);
    k_pass1<<<NEDGE/4/256, 256, 0, stream>>>(edges, markT, cnts, e0);
    k_dedup<<<NPOS, 256, 0, stream>>>(e0, cnts, markT, Tnodes);
    k_pass2<<<NEDGE/4/256, 256, 0, stream>>>(edges, markT, e1cnt, e1, degCnt);
    k_pass3<<<NEDGE/4/256, 256, 0, stream>>>(edges, markT, degCnt);
    k_aggT<<<(TCAP+3)/4, 256, 0, stream>>>(e1cnt, e1, degCnt, cnts, graph_x, axT);
    k_h12T<<<2*((TCAP+127)/128), 256, 0, stream>>>(axT, Tnodes, degCnt, cnts,
                                                   graph_x, W1, b1, W2, hsT);
    k_mlp1<<<NB*16, 256, 0, stream>>>(pos2t0, posNode, e1cnt, e1, markT, hsT,
                                      degCnt, b2, actions, steps, Wp1, bp1, hm);
    k_mlp2<<<NB*16, 256, 0, stream>>>(hm, Wp2, bp2, out);
}

// Round 4
// 171.642 us; speedup vs baseline: 3.5550x; 3.5550x over previous
//
#include <hip/hip_runtime.h>

#define NB 8
#define NN 10000
#define NE 160000
#define NNODES (NB*NN)          // 80000
#define NEDGE (NB*NE)           // 1280000
#define FIN 5
#define HID 128
#define EMB 256
#define ALAST 10
#define PROJ_IN (HID*5 + ALAST + 1)  // 651
#define NPOS 40                      // 5 positions x 8 batches
#define E0CAP 256                    // in-edges kept per position node
#define TCAP (NPOS + NPOS*E0CAP)     // 10280 max T slots (realistically ~720)
#define E1C 128                      // in-edges kept per T slot (Poisson(16))
#define BMW (NNODES/32)              // 2500 bitmap words

// markT encoding: -1 none, >=0 T slot, -2 transient CAS claim.
// cnts: [0]=nT; per-position e0 counters at stride-16 ints (64B padded).
#define C_NT 0
#define C_E0(t) (8 + (t)*16)

// tiny: zero the cnts block (must be 0 before k_scan1's e0 atomics)
__global__ __launch_bounds__(256) void k_zcnts(int* __restrict__ cnts) {
    for (int i = threadIdx.x; i < 1024; i += 256) cnts[i] = 0;
}

// Fused init + pass1. Every block rebuilds the 40-position table + a 10KB
// LDS bitmap of the 80K nodes; the edge scan then tests dst membership in
// LDS (no random global gathers at all). Grid-strided clears of
// markT/degCnt/e1cnt/bmT/bmF ride along (consumed only by later kernels).
__global__ __launch_bounds__(256) void k_scan1(
        const int* __restrict__ edges, const int* __restrict__ avail,
        const int* __restrict__ pos,
        int* __restrict__ markT, int* __restrict__ degCnt,
        int* __restrict__ e1cnt, int* __restrict__ cnts,
        unsigned int* __restrict__ bmT, unsigned int* __restrict__ bmF,
        int* __restrict__ Tnodes, int* __restrict__ pos2t0,
        int* __restrict__ posNode, int* __restrict__ e0) {
    __shared__ unsigned int bm[BMW];
    __shared__ int pnode[NPOS], pslot[NPOS];
    const int t = threadIdx.x;
    const int gtid = blockIdx.x*256 + t;

    if (t < 64) {                       // wave 0: 40-position dedupe table
        int p = t, n = -1;
        if (p < NPOS) {
            int b = p / 5, pi = p - b*5;
            int node = (pi < 4) ? avail[b*4 + pi] : pos[b];
            n = node + b*NN;
        }
        int firstIdx = p;
        for (int q = 0; q < NPOS; ++q) {
            int nq = __shfl(n, q, 64);
            if (p < NPOS && q < p && nq == n && firstIdx == p) firstIdx = q;
        }
        bool isFirst = (p < NPOS) && (firstIdx == p);
        unsigned long long bal = __ballot(isFirst);
        if (p < NPOS) {
            int slot = __popcll(bal & ((1ull << firstIdx) - 1ull));
            pnode[p] = n; pslot[p] = slot;
            if (blockIdx.x == 0) {
                pos2t0[p] = slot; posNode[p] = n;
                if (isFirst) Tnodes[slot] = n;
            }
        }
        if (p == 0 && blockIdx.x == 0) cnts[C_NT] = __popcll(bal);
    }
    for (int w = t; w < BMW; w += 256) bm[w] = 0u;
    __syncthreads();
    if (t < NPOS) {
        int n = pnode[t];
        atomicOr(&bm[n >> 5], 1u << (n & 31));
    }
    __syncthreads();

    // grid-strided clears (grid = 625*256 = 160000 threads)
    if (gtid < NNODES) {
        int mk = -1;
        if ((bm[gtid >> 5] >> (gtid & 31)) & 1u) {
            #pragma unroll
            for (int p = 0; p < NPOS; ++p)
                if (pnode[p] == gtid) { mk = pslot[p]; break; }
        }
        markT[gtid] = mk;
        degCnt[gtid] = 0;
    }
    if (gtid < TCAP*4) e1cnt[gtid] = 0;
    if (gtid < BMW) { bmT[gtid] = bm[gtid]; bmF[gtid] = 0u; }

    // edge scan: 8 edges/thread, LDS bitmap test only
    int g  = gtid / (NE/8);
    int w8 = gtid - g*(NE/8);
    const int* base = edges + (size_t)g*2*NE;
    const int4* dst4 = (const int4*)(base + NE);
    int4 da = dst4[2*w8], db = dst4[2*w8+1];
    int gofs = g*NN;
    int dd[8] = {da.x, da.y, da.z, da.w, db.x, db.y, db.z, db.w};
    #pragma unroll
    for (int c = 0; c < 8; ++c) {
        int d = gofs + dd[c];
        if ((bm[d >> 5] >> (d & 31)) & 1u) {
            int slot = -1;
            #pragma unroll
            for (int p = 0; p < NPOS; ++p)
                if (pnode[p] == d) { slot = pslot[p]; break; }
            int s = base[8*w8 + c] + gofs;
            int k = atomicAdd(&cnts[C_E0(slot)], 1);
            if (k < E0CAP) e0[slot*E0CAP + k] = s;
        }
    }
}

// dedup, parallel: 40 blocks (one per e0 list); also sets the T bitmap bit.
__global__ __launch_bounds__(256) void k_dedup(const int* __restrict__ e0,
                        int* __restrict__ cnts, int* __restrict__ markT,
                        int* __restrict__ Tnodes, unsigned int* __restrict__ bmT) {
    __shared__ int lc, base;
    int t0 = blockIdx.x;
    if (threadIdx.x == 0) lc = 0;
    __syncthreads();
    int m = cnts[C_E0(t0)]; if (m > E0CAP) m = E0CAP;
    int s = -1, myIdx = -1;
    if ((int)threadIdx.x < m) {
        s = e0[t0*E0CAP + threadIdx.x];
        if (atomicCAS(&markT[s], -1, -2) == -1)
            myIdx = atomicAdd(&lc, 1);              // LDS atomic
    }
    __syncthreads();
    if (threadIdx.x == 0 && lc > 0) base = atomicAdd(&cnts[C_NT], lc);
    __syncthreads();
    if (myIdx >= 0) {
        int slot = base + myIdx;                    // < TCAP by construction
        Tnodes[slot] = s;
        markT[s] = slot;
        atomicOr(&bmT[s >> 5], 1u << (s & 31));
    }
}

// pass2: dst tested against the 10KB T bitmap (L1-resident); markT gather
// only on the rare hit. Frontier sources recorded in bmF (rare atomicOr).
__global__ __launch_bounds__(256) void k_pass2(const int* __restrict__ edges,
        const unsigned int* __restrict__ bmT, const int* __restrict__ markT,
        int* __restrict__ e1cnt, int* __restrict__ e1,
        int* __restrict__ degCnt, unsigned int* __restrict__ bmF) {
    int idx = blockIdx.x*256 + threadIdx.x;
    int g  = idx / (NE/8);
    int w8 = idx - g*(NE/8);
    const int* base = edges + (size_t)g*2*NE;
    const int4* dst4 = (const int4*)(base + NE);
    int4 da = dst4[2*w8], db = dst4[2*w8+1];
    int gofs = g*NN;
    int dd[8] = {da.x, da.y, da.z, da.w, db.x, db.y, db.z, db.w};
    #pragma unroll
    for (int c = 0; c < 8; ++c) {
        int d = gofs + dd[c];
        if ((bmT[d >> 5] >> (d & 31)) & 1u) {
            int ts = markT[d];
            int s = base[8*w8 + c] + gofs;
            int k = atomicAdd(&e1cnt[ts*4], 1);     // 16B-padded counter
            if (k < E1C) e1[(size_t)ts*E1C + k] = s;
            atomicAdd(&degCnt[d], 1);               // T-node degree
            if (!((bmT[s >> 5] >> (s & 31)) & 1u))  // frontier (not in T)
                atomicOr(&bmF[s >> 5], 1u << (s & 31));
        }
    }
}

// pass3: dst tested against the 10KB frontier bitmap (L1-resident).
__global__ __launch_bounds__(256) void k_pass3(const int* __restrict__ edges,
        const unsigned int* __restrict__ bmF, int* __restrict__ degCnt) {
    int idx = blockIdx.x*256 + threadIdx.x;
    int g  = idx / (NE/8);
    int w8 = idx - g*(NE/8);
    const int4* dst4 = (const int4*)(edges + (size_t)g*2*NE + NE);
    int4 da = dst4[2*w8], db = dst4[2*w8+1];
    int gofs = g*NN;
    int dd[8] = {da.x, da.y, da.z, da.w, db.x, db.y, db.z, db.w};
    #pragma unroll
    for (int c = 0; c < 8; ++c) {
        int d = gofs + dd[c];
        if ((bmF[d >> 5] >> (d & 31)) & 1u) atomicAdd(&degCnt[d], 1);
    }
}

// aggT: layer-1 aggregation, one WAVE per T slot.
__global__ __launch_bounds__(256) void k_aggT(
        const int* __restrict__ e1cnt, const int* __restrict__ e1,
        const int* __restrict__ degCnt, const int* __restrict__ cnts,
        const float* __restrict__ xg, float* __restrict__ axT) {
    int slot = blockIdx.x*4 + (threadIdx.x >> 6);
    int lane = threadIdx.x & 63;
    int ntv = cnts[C_NT]; if (ntv > TCAP) ntv = TCAP;
    if (slot >= ntv) return;
    int m = e1cnt[slot*4]; if (m > E1C) m = E1C;
    float acc[FIN] = {0.f, 0.f, 0.f, 0.f, 0.f};
    for (int j = lane; j < m; j += 64) {
        int s = e1[(size_t)slot*E1C + j];
        float dv = rsqrtf(1.0f + (float)degCnt[s]);
        const float* xr = xg + (size_t)s*FIN;
        #pragma unroll
        for (int f = 0; f < FIN; ++f) acc[f] += xr[f]*dv;
    }
    #pragma unroll
    for (int f = 0; f < FIN; ++f) {
        #pragma unroll
        for (int d = 32; d; d >>= 1) acc[f] += __shfl_down(acc[f], d, 64);
    }
    if (lane == 0) {
        #pragma unroll
        for (int f = 0; f < FIN; ++f) axT[(size_t)slot*FIN + f] = acc[f];
    }
}

// Fused layer-1 dense + layer-2 dense over T slots; A-tile = axT + self term.
#define KC 32
__global__ __launch_bounds__(256) void k_h12T(
        const float* __restrict__ axT, const int* __restrict__ Tnodes,
        const int* __restrict__ degCnt, const int* __restrict__ cnts,
        const float* __restrict__ xg,
        const float* __restrict__ W1, const float* __restrict__ b1,
        const float* __restrict__ W2, float* __restrict__ hsT) {
    __shared__ float axs[FIN][128];
    __shared__ float w1s[FIN][128];
    __shared__ float b1s[128];
    __shared__ float dvs[128];
    __shared__ float xs[KC*128];
    __shared__ float wt[KC*64];
    int ntv = cnts[C_NT]; if (ntv > TCAP) ntv = TCAP;
    int jb  = blockIdx.x & 1;
    int m0g = (blockIdx.x >> 1) * 128;
    if (m0g >= ntv) return;
    int tid = threadIdx.x;
    if (tid < 128) {
        b1s[tid] = b1[tid];
        #pragma unroll
        for (int f = 0; f < FIN; ++f) w1s[f][tid] = W1[tid*FIN + f];
    } else {
        int r2 = tid - 128;
        int row = m0g + r2;
        int ok = row < ntv;
        int node = ok ? Tnodes[row] : 0;
        float dvv = ok ? rsqrtf(1.0f + (float)degCnt[node]) : 0.0f;
        dvs[r2] = dvv;
        #pragma unroll
        for (int f = 0; f < FIN; ++f)
            axs[f][r2] = ok ? (axT[(size_t)row*FIN + f]
                               + xg[(size_t)node*FIN + f]*dvv) : 0.0f;
    }
    int tx = tid & 15, ty = tid >> 4;
    int m0 = ty*8;
    int j0 = tx*4;
    int r  = tid >> 1;
    int kq = (tid & 1) * 16;
    int rw  = tid >> 2;
    int kqw = (tid & 3) * 8;
    float a[8][4];
    #pragma unroll
    for (int i = 0; i < 8; ++i)
        #pragma unroll
        for (int j = 0; j < 4; ++j) a[i][j] = 0.f;
    __syncthreads();
    float axr[FIN];
    float dvr = dvs[r];
    #pragma unroll
    for (int f = 0; f < FIN; ++f) axr[f] = axs[f][r] * dvr;

    for (int kh = 0; kh < 128; kh += KC) {
        float4 wv0 = *(const float4*)&W2[(size_t)(jb*64 + rw)*128 + kh + kqw];
        float4 wv1 = *(const float4*)&W2[(size_t)(jb*64 + rw)*128 + kh + kqw + 4];
        float hv[16];
        #pragma unroll
        for (int kk = 0; kk < 16; ++kk) {
            int k1 = kh + kq + kk;
            float sv = b1s[k1];
            #pragma unroll
            for (int f = 0; f < FIN; ++f) sv += axr[f]*w1s[f][k1];
            hv[kk] = fmaxf(sv, 0.0f);
        }
        __syncthreads();
        #pragma unroll
        for (int kk = 0; kk < 16; ++kk) xs[(kq+kk)*128 + r] = hv[kk];
        wt[(kqw+0)*64 + rw] = wv0.x;
        wt[(kqw+1)*64 + rw] = wv0.y;
        wt[(kqw+2)*64 + rw] = wv0.z;
        wt[(kqw+3)*64 + rw] = wv0.w;
        wt[(kqw+4)*64 + rw] = wv1.x;
        wt[(kqw+5)*64 + rw] = wv1.y;
        wt[(kqw+6)*64 + rw] = wv1.z;
        wt[(kqw+7)*64 + rw] = wv1.w;
        __syncthreads();
        for (int k = 0; k < KC; ++k) {
            float4 xa = *(const float4*)&xs[k*128 + m0];
            float4 xb = *(const float4*)&xs[k*128 + m0 + 4];
            float4 wa = *(const float4*)&wt[k*64 + j0];
            float xr[8] = {xa.x,xa.y,xa.z,xa.w,xb.x,xb.y,xb.z,xb.w};
            #pragma unroll
            for (int i = 0; i < 8; ++i) {
                a[i][0] += xr[i]*wa.x;
                a[i][1] += xr[i]*wa.y;
                a[i][2] += xr[i]*wa.z;
                a[i][3] += xr[i]*wa.w;
            }
        }
    }
    #pragma unroll
    for (int i = 0; i < 8; ++i) {
        int row = m0g + m0 + i;
        if (row < ntv) {
            float dv = dvs[m0 + i];
            float4 v0 = make_float4(a[i][0]*dv, a[i][1]*dv, a[i][2]*dv, a[i][3]*dv);
            *(float4*)&hsT[(size_t)row*HID + jb*64 + j0] = v0;
        }
    }
}

// MLP1 with fused layer-2 aggregation: block per (batch, 16-output group).
__global__ __launch_bounds__(256) void k_mlp1(
        const int* __restrict__ pos2t0, const int* __restrict__ posNode,
        const int* __restrict__ e1cnt, const int* __restrict__ e1,
        const int* __restrict__ markT, const float* __restrict__ hsT,
        const int* __restrict__ degCnt, const float* __restrict__ b2,
        const float* __restrict__ actions, const float* __restrict__ steps,
        const float* __restrict__ Wp1, const float* __restrict__ bp1,
        float* __restrict__ hm) {
    int b  = blockIdx.x >> 4;
    int jg = blockIdx.x & 15;
    int t  = threadIdx.x;
    __shared__ float c[PROJ_IN];
    __shared__ int slots[5*E1C];
    __shared__ int cm[5], t0s[5];
    __shared__ float dvP[5];
    if (t < 5) {
        int t0 = pos2t0[b*5 + t];
        t0s[t] = t0;
        int m = e1cnt[t0*4]; if (m > E1C) m = E1C;
        cm[t] = m;
        dvP[t] = rsqrtf(1.0f + (float)degCnt[posNode[b*5 + t]]);
    }
    __syncthreads();
    for (int i = t; i < 5*E1C; i += 256) {
        int p5 = i >> 7, j = i & (E1C-1);
        if (j < cm[p5]) slots[i] = markT[e1[(size_t)t0s[p5]*E1C + j]];
    }
    __syncthreads();
    for (int i = t; i < 5*HID; i += 256) {
        int p5 = i >> 7, f = i & 127;
        float acc = hsT[(size_t)t0s[p5]*HID + f];
        int m = cm[p5];
        const int* sp = &slots[p5*E1C];
        for (int j = 0; j < m; ++j) {
            int ts = sp[j];
            if (ts >= 0) acc += hsT[(size_t)ts*HID + f];
        }
        c[i] = fmaxf(acc*dvP[p5] + b2[f], 0.0f);
    }
    if (t < ALAST) c[5*HID + t] = actions[b*ALAST + t];
    if (t == ALAST) c[5*HID + ALAST] = steps[b];
    __syncthreads();
    int o = t >> 4, sub = t & 15;
    int j = jg*16 + o;
    const float* wr = Wp1 + (size_t)j*PROJ_IN;
    float s = 0.f;
    for (int k = sub; k < PROJ_IN; k += 16) s += c[k]*wr[k];
    #pragma unroll
    for (int d = 8; d; d >>= 1) s += __shfl_down(s, d, 16);
    if (sub == 0) hm[b*EMB + j] = fmaxf(s + bp1[j], 0.f);
}

// MLP2
__global__ __launch_bounds__(256) void k_mlp2(
        const float* __restrict__ hm, const float* __restrict__ Wp2,
        const float* __restrict__ bp2, float* __restrict__ out) {
    int b  = blockIdx.x >> 4;
    int jg = blockIdx.x & 15;
    int t  = threadIdx.x;
    __shared__ float c[EMB];
    if (t < EMB) c[t] = hm[b*EMB + t];
    __syncthreads();
    int o = t >> 4, sub = t & 15;
    int j = jg*16 + o;
    const float* wr = Wp2 + (size_t)j*EMB;
    float s = 0.f;
    for (int k = sub; k < EMB; k += 16) s += c[k]*wr[k];
    #pragma unroll
    for (int d = 8; d; d >>= 1) s += __shfl_down(s, d, 16);
    if (sub == 0) out[b*EMB + j] = s + bp2[j];
}

extern "C" void kernel_launch(void* const* d_in, const int* in_sizes, int n_in,
                              void* d_out, int out_size, void* d_ws, size_t ws_size,
                              hipStream_t stream) {
    const float* graph_x = (const float*)d_in[0];
    const int*   edges   = (const int*)d_in[1];
    const int*   pos     = (const int*)d_in[2];
    const int*   avail   = (const int*)d_in[3];
    const float* actions = (const float*)d_in[4];
    const float* steps   = (const float*)d_in[5];
    const float* W1  = (const float*)d_in[6];
    const float* b1  = (const float*)d_in[7];
    const float* W2  = (const float*)d_in[8];
    const float* b2  = (const float*)d_in[9];
    const float* Wp1 = (const float*)d_in[10];
    const float* bp1 = (const float*)d_in[11];
    const float* Wp2 = (const float*)d_in[12];
    const float* bp2 = (const float*)d_in[13];
    float* out = (float*)d_out;

    char* ws = (char*)d_ws;
    size_t off = 0;
    #define ALLOC(ptrname, type, nelem) \
        type* ptrname = (type*)(ws + off); off = (off + (size_t)(nelem)*sizeof(type) + 255) & ~(size_t)255;
    ALLOC(markT,   int,   NNODES)
    ALLOC(degCnt,  int,   NNODES)
    ALLOC(cnts,    int,   1024)
    ALLOC(e1cnt,   int,   TCAP*4)
    ALLOC(Tnodes,  int,   TCAP)
    ALLOC(pos2t0,  int,   NPOS)
    ALLOC(posNode, int,   NPOS)
    ALLOC(e0,      int,   NPOS*E0CAP)
    ALLOC(e1,      int,   (size_t)TCAP*E1C)
    ALLOC(axT,     float, (size_t)(TCAP+128)*FIN)
    ALLOC(hsT,     float, (size_t)TCAP*HID)
    ALLOC(hm,      float, (size_t)NB*EMB)
    ALLOC(bmT,     unsigned int, BMW + 64)
    ALLOC(bmF,     unsigned int, BMW + 64)
    #undef ALLOC

    k_zcnts<<<1, 256, 0, stream>>>(cnts);
    k_scan1<<<NEDGE/8/256, 256, 0, stream>>>(edges, avail, pos, markT, degCnt,
                                             e1cnt, cnts, bmT, bmF,
                                             Tnodes, pos2t0, posNode, e0);
    k_dedup<<<NPOS, 256, 0, stream>>>(e0, cnts, markT, Tnodes, bmT);
    k_pass2<<<NEDGE/8/256, 256, 0, stream>>>(edges, bmT, markT, e1cnt, e1,
                                             degCnt, bmF);
    k_pass3<<<NEDGE/8/256, 256, 0, stream>>>(edges, bmF, degCnt);
    k_aggT<<<(TCAP+3)/4, 256, 0, stream>>>(e1cnt, e1, degCnt, cnts, graph_x, axT);
    k_h12T<<<2*((TCAP+127)/128), 256, 0, stream>>>(axT, Tnodes, degCnt, cnts,
                                                   graph_x, W1, b1, W2, hsT);
    k_mlp1<<<NB*16, 256, 0, stream>>>(pos2t0, posNode, e1cnt, e1, markT, hsT,
                                      degCnt, b2, actions, steps, Wp1, bp1, hm);
    k_mlp2<<<NB*16, 256, 0, stream>>>(hm, Wp2, bp2, out);
}